// Round 1
// baseline (3093.671 us; speedup 1.0000x reference)
//
#include <hip/hip_runtime.h>
#include <hip/hip_bf16.h>

#define N_NODE 100000
#define EMB 112
#define NNZ 1000000
#define BATCH 512
#define SEQL 50
#define LAYERS 2

// ---------------------------------------------------------------------------
// SpMM: out[r] += v * cur[c] for each edge (r, c, v).
// 32 lanes per edge; lanes 0..27 each handle one float4 of the 112-float row.
// Coalesced 448B gather per edge; 4 f32 atomicAdds per active lane.
// ---------------------------------------------------------------------------
__global__ void spmm_kernel(const float* __restrict__ cur,
                            const float* __restrict__ vals,
                            const int* __restrict__ rows,
                            const int* __restrict__ cols,
                            float* __restrict__ out, int nnz) {
    long long gid = (long long)blockIdx.x * blockDim.x + threadIdx.x;
    int edge = (int)(gid >> 5);
    int lane = (int)(gid & 31);
    if (edge >= nnz) return;
    int r = rows[edge];
    int c = cols[edge];
    float v = vals[edge];
    if (lane < EMB / 4) {  // 28 float4s
        float4 x = ((const float4*)(cur + (size_t)c * EMB))[lane];
        float* dst = out + (size_t)r * EMB + lane * 4;
        atomicAdd(dst + 0, v * x.x);
        atomicAdd(dst + 1, v * x.y);
        atomicAdd(dst + 2, v * x.z);
        atomicAdd(dst + 3, v * x.w);
    }
}

// ---------------------------------------------------------------------------
// Pool: sess[b] = sum_l item_emb[session_item[b][l]] / (3 * session_len[b])
// item_emb[i] = emb[i] + n1[i] + n2[i]  (never materialized); item 0 = pad.
// One block per session row; thread f handles feature f.
// Also initializes acc = sess.
// ---------------------------------------------------------------------------
__global__ void pool_kernel(const float* __restrict__ emb,
                            const float* __restrict__ n1,
                            const float* __restrict__ n2,
                            const int* __restrict__ items,
                            const float* __restrict__ slen,
                            float* __restrict__ sess,
                            float* __restrict__ acc) {
    int b = blockIdx.x;
    int f = threadIdx.x;
    if (f >= EMB) return;
    float s = 0.0f;
    for (int l = 0; l < SEQL; ++l) {
        int it = items[b * SEQL + l];
        if (it > 0) {
            size_t idx = (size_t)(it - 1) * EMB + f;
            s += emb[idx] + n1[idx] + n2[idx];
        }
    }
    s = s * (1.0f / 3.0f) / slen[b];
    sess[b * EMB + f] = s;
    acc[b * EMB + f] = s;
}

// ---------------------------------------------------------------------------
// DA = D @ A, 512x512x512 fp32, 16x16 LDS-tiled (no fp32 MFMA on CDNA4).
// ---------------------------------------------------------------------------
#define TS 16
__global__ void gemm_da_kernel(const float* __restrict__ D,
                               const float* __restrict__ A,
                               float* __restrict__ DA) {
    __shared__ float sD[TS][TS];
    __shared__ float sA[TS][TS + 1];
    int row = blockIdx.y * TS + threadIdx.y;
    int col = blockIdx.x * TS + threadIdx.x;
    float acc = 0.0f;
    for (int k0 = 0; k0 < BATCH; k0 += TS) {
        sD[threadIdx.y][threadIdx.x] = D[row * BATCH + k0 + threadIdx.x];
        sA[threadIdx.y][threadIdx.x] = A[(k0 + threadIdx.y) * BATCH + col];
        __syncthreads();
#pragma unroll
        for (int k = 0; k < TS; ++k)
            acc += sD[threadIdx.y][k] * sA[k][threadIdx.x];
        __syncthreads();
    }
    DA[row * BATCH + col] = acc;
}

// ---------------------------------------------------------------------------
// t = sess @ W^T  (W = w_sess[i], [112,112]); t[b][j] = dot(sess[b,:], W[j,:])
// One block per b; sess row staged in LDS.
// ---------------------------------------------------------------------------
__global__ void lin_kernel(const float* __restrict__ sess,
                           const float* __restrict__ W,
                           float* __restrict__ t) {
    __shared__ float srow[EMB];
    int b = blockIdx.x;
    int j = threadIdx.x;
    if (j < EMB) srow[j] = sess[b * EMB + j];
    __syncthreads();
    if (j >= EMB) return;
    float a = 0.0f;
    for (int k = 0; k < EMB; ++k) a += srow[k] * W[j * EMB + k];
    t[b * EMB + j] = a;
}

// ---------------------------------------------------------------------------
// s2 = l2norm_row(DA @ t); sess = s2; acc += s2; if final: out = acc / 3.
// One block (128 threads = 2 waves) per row b; thread j computes column j.
// ---------------------------------------------------------------------------
__global__ void damul_norm_kernel(const float* __restrict__ DA,
                                  const float* __restrict__ t,
                                  float* __restrict__ sess,
                                  float* __restrict__ acc,
                                  float* __restrict__ out, int final_layer) {
    int b = blockIdx.x;
    int j = threadIdx.x;  // 0..127, j<112 active for compute
    float v = 0.0f;
    if (j < EMB) {
        const float* darow = DA + (size_t)b * BATCH;
        for (int k = 0; k < BATCH; ++k) v += darow[k] * t[k * EMB + j];
    }
    // block-reduce sum of squares across 128 threads (2 waves)
    float sq = (j < EMB) ? v * v : 0.0f;
#pragma unroll
    for (int off = 32; off > 0; off >>= 1) sq += __shfl_down(sq, off, 64);
    __shared__ float partial[2];
    if ((j & 63) == 0) partial[j >> 6] = sq;
    __syncthreads();
    float norm = sqrtf(partial[0] + partial[1]);
    float inv = 1.0f / fmaxf(norm, 1e-12f);
    if (j < EMB) {
        float s = v * inv;
        sess[b * EMB + j] = s;
        float a = acc[b * EMB + j] + s;
        acc[b * EMB + j] = a;
        if (final_layer) out[b * EMB + j] = a * (1.0f / 3.0f);
    }
}

extern "C" void kernel_launch(void* const* d_in, const int* in_sizes, int n_in,
                              void* d_out, int out_size, void* d_ws, size_t ws_size,
                              hipStream_t stream) {
    const float* embedding = (const float*)d_in[0];   // [100000,112]
    const float* adj_vals  = (const float*)d_in[1];   // [1e6]
    const int*   adj_rows  = (const int*)d_in[2];     // [1e6]
    const int*   adj_cols  = (const int*)d_in[3];     // [1e6]
    const float* D         = (const float*)d_in[4];   // [512,512]
    const float* A         = (const float*)d_in[5];   // [512,512]
    const int*   sess_item = (const int*)d_in[6];     // [512,50]
    const float* sess_len  = (const float*)d_in[7];   // [512,1]
    const float* w_sess    = (const float*)d_in[8];   // [2,112,112]
    float* out = (float*)d_out;                       // [512,112]

    // Workspace layout (all offsets 256B-aligned)
    const size_t NODE_BYTES = (size_t)N_NODE * EMB * sizeof(float);  // 44,800,000
    char* ws = (char*)d_ws;
    float* next1 = (float*)(ws);                      // 44.8 MB
    float* next2 = (float*)(ws + NODE_BYTES);         // 44.8 MB
    float* DA    = (float*)(ws + 2 * NODE_BYTES);                       // 1 MB
    float* sess  = (float*)(ws + 2 * NODE_BYTES + 1048576);             // 229 KB
    float* tbuf  = (float*)(ws + 2 * NODE_BYTES + 1048576 + 229376);    // 229 KB
    float* accb  = (float*)(ws + 2 * NODE_BYTES + 1048576 + 2 * 229376);// 229 KB

    // zero the two scatter targets (ws is poisoned 0xAA before every launch)
    hipMemsetAsync(next1, 0, 2 * NODE_BYTES, stream);

    // hyperconv: next1 = S(emb); next2 = S(next1)
    {
        long long threads = (long long)NNZ * 32;
        int blocks = (int)((threads + 255) / 256);
        spmm_kernel<<<blocks, 256, 0, stream>>>(embedding, adj_vals, adj_rows,
                                                adj_cols, next1, NNZ);
        spmm_kernel<<<blocks, 256, 0, stream>>>(next1, adj_vals, adj_rows,
                                                adj_cols, next2, NNZ);
    }

    // pool: sess = acc = sum_l item_emb[items]/(3*len)
    pool_kernel<<<BATCH, 128, 0, stream>>>(embedding, next1, next2, sess_item,
                                           sess_len, sess, accb);

    // DA = D @ A
    {
        dim3 grid(BATCH / TS, BATCH / TS);
        dim3 block(TS, TS);
        gemm_da_kernel<<<grid, block, 0, stream>>>(D, A, DA);
    }

    // two sessconv layers
    for (int i = 0; i < LAYERS; ++i) {
        lin_kernel<<<BATCH, 128, 0, stream>>>(sess, w_sess + (size_t)i * EMB * EMB, tbuf);
        damul_norm_kernel<<<BATCH, 128, 0, stream>>>(DA, tbuf, sess, accb, out,
                                                     i == LAYERS - 1);
    }
}

// Round 2
// 858.893 us; speedup vs baseline: 3.6019x; 3.6019x over previous
//
#include <hip/hip_runtime.h>
#include <hip/hip_bf16.h>

#define N_NODE 100000
#define EMB 112
#define NNZ 1000000
#define BATCH 512
#define SEQL 50
#define LAYERS 2

// ---------------------------------------------------------------------------
// Counting sort of edges by destination row -> CSR permutation.
// ---------------------------------------------------------------------------
__global__ void hist_kernel(const int* __restrict__ rows, int* __restrict__ cnt,
                            int nnz) {
    int i = blockIdx.x * blockDim.x + threadIdx.x;
    if (i < nnz) atomicAdd(&cnt[rows[i]], 1);
}

// In-place exclusive scan, 1024 elements per block (256 thr x 4), block sums out.
#define SCAN_B 1024
__global__ void scan_block_kernel(int* __restrict__ a, int* __restrict__ bsum,
                                  int n) {
    __shared__ int s[256];
    int t = threadIdx.x;
    int base = blockIdx.x * SCAN_B + t * 4;
    int v0 = (base + 0 < n) ? a[base + 0] : 0;
    int v1 = (base + 1 < n) ? a[base + 1] : 0;
    int v2 = (base + 2 < n) ? a[base + 2] : 0;
    int v3 = (base + 3 < n) ? a[base + 3] : 0;
    int tsum = v0 + v1 + v2 + v3;
    s[t] = tsum;
    __syncthreads();
#pragma unroll
    for (int d = 1; d < 256; d <<= 1) {
        int x = (t >= d) ? s[t - d] : 0;
        __syncthreads();
        s[t] += x;
        __syncthreads();
    }
    int excl = s[t] - tsum;
    if (t == 255) bsum[blockIdx.x] = s[255];
    if (base + 0 < n) a[base + 0] = excl;
    if (base + 1 < n) a[base + 1] = excl + v0;
    if (base + 2 < n) a[base + 2] = excl + v0 + v1;
    if (base + 3 < n) a[base + 3] = excl + v0 + v1 + v2;
}

__global__ void scan_sums_kernel(int* __restrict__ bsum, int nb) {
    __shared__ int s[128];
    int t = threadIdx.x;
    int v = (t < nb) ? bsum[t] : 0;
    s[t] = v;
    __syncthreads();
#pragma unroll
    for (int d = 1; d < 128; d <<= 1) {
        int x = (t >= d) ? s[t - d] : 0;
        __syncthreads();
        s[t] += x;
        __syncthreads();
    }
    if (t < nb) bsum[t] = s[t] - v;  // exclusive
}

__global__ void scan_add_kernel(int* __restrict__ a, const int* __restrict__ bsum,
                                int n) {
    int i = blockIdx.x * blockDim.x + threadIdx.x;
    if (i < n) a[i] += bsum[i >> 10];
}

// p = atomicAdd(&off[r],1): writes perm; afterwards off[r] == row-end pointer.
__global__ void scatter_kernel(const int* __restrict__ rows,
                               int* __restrict__ off, int* __restrict__ perm,
                               int nnz) {
    int i = blockIdx.x * blockDim.x + threadIdx.x;
    if (i >= nnz) return;
    int r = rows[i];
    int p = atomicAdd(&off[r], 1);
    perm[p] = i;
}

// ---------------------------------------------------------------------------
// CSR gather SpMM: out[r] = sum_{e in row r} vals[e] * cur[cols[e]]
// 128 threads own one row (thread j = feature j); 2 rows per 256-block.
// fuse_final: out[r] = (out[r] + cur[r] + emb[r]) / 3  (item_emb, never
// materializing next2 separately).
// rend[r] is the END of row r's segment; start is rend[r-1] (0 for r=0).
// ---------------------------------------------------------------------------
__global__ void spmm_csr_kernel(const float* __restrict__ cur,
                                const float* __restrict__ emb,
                                const int* __restrict__ rend,
                                const int* __restrict__ perm,
                                const int* __restrict__ cols,
                                const float* __restrict__ vals,
                                float* __restrict__ outm, int fuse_final) {
    int r = (blockIdx.x << 1) | (threadIdx.x >> 7);
    int j = threadIdx.x & 127;
    if (r >= N_NODE || j >= EMB) return;
    int beg = (r == 0) ? 0 : rend[r - 1];
    int end = rend[r];
    float acc = 0.0f;
    for (int k = beg; k < end; ++k) {
        int e = perm[k];
        acc += vals[e] * cur[(size_t)cols[e] * EMB + j];
    }
    size_t o = (size_t)r * EMB + j;
    if (fuse_final) acc = (acc + cur[o] + emb[o]) * (1.0f / 3.0f);
    outm[o] = acc;
}

// ---------------------------------------------------------------------------
// Pool: sess[b] = sum_l item[session_item[b][l]-1] / session_len[b]
// (item already carries the /3). Also acc = sess.
// ---------------------------------------------------------------------------
__global__ void pool_kernel(const float* __restrict__ item,
                            const int* __restrict__ items,
                            const float* __restrict__ slen,
                            float* __restrict__ sess, float* __restrict__ acc) {
    int b = blockIdx.x;
    int f = threadIdx.x;
    if (f >= EMB) return;
    float s = 0.0f;
    for (int l = 0; l < SEQL; ++l) {
        int it = items[b * SEQL + l];
        if (it > 0) s += item[(size_t)(it - 1) * EMB + f];
    }
    s /= slen[b];
    sess[b * EMB + f] = s;
    acc[b * EMB + f] = s;
}

// ---------------------------------------------------------------------------
// DA = D @ A, 512x512x512 fp32, 16x16 LDS-tiled (no fp32 MFMA on CDNA4).
// ---------------------------------------------------------------------------
#define TS 16
__global__ void gemm_da_kernel(const float* __restrict__ D,
                               const float* __restrict__ A,
                               float* __restrict__ DA) {
    __shared__ float sD[TS][TS];
    __shared__ float sA[TS][TS + 1];
    int row = blockIdx.y * TS + threadIdx.y;
    int col = blockIdx.x * TS + threadIdx.x;
    float acc = 0.0f;
    for (int k0 = 0; k0 < BATCH; k0 += TS) {
        sD[threadIdx.y][threadIdx.x] = D[row * BATCH + k0 + threadIdx.x];
        sA[threadIdx.y][threadIdx.x] = A[(k0 + threadIdx.y) * BATCH + col];
        __syncthreads();
#pragma unroll
        for (int k = 0; k < TS; ++k)
            acc += sD[threadIdx.y][k] * sA[k][threadIdx.x];
        __syncthreads();
    }
    DA[row * BATCH + col] = acc;
}

// ---------------------------------------------------------------------------
// t = sess @ W^T
// ---------------------------------------------------------------------------
__global__ void lin_kernel(const float* __restrict__ sess,
                           const float* __restrict__ W,
                           float* __restrict__ t) {
    __shared__ float srow[EMB];
    int b = blockIdx.x;
    int j = threadIdx.x;
    if (j < EMB) srow[j] = sess[b * EMB + j];
    __syncthreads();
    if (j >= EMB) return;
    float a = 0.0f;
    for (int k = 0; k < EMB; ++k) a += srow[k] * W[j * EMB + k];
    t[b * EMB + j] = a;
}

// ---------------------------------------------------------------------------
// s2 = l2norm_row(DA @ t); sess = s2; acc += s2; if final: out = acc / 3.
// ---------------------------------------------------------------------------
__global__ void damul_norm_kernel(const float* __restrict__ DA,
                                  const float* __restrict__ t,
                                  float* __restrict__ sess,
                                  float* __restrict__ acc,
                                  float* __restrict__ out, int final_layer) {
    int b = blockIdx.x;
    int j = threadIdx.x;  // 0..127
    float v = 0.0f;
    if (j < EMB) {
        const float* darow = DA + (size_t)b * BATCH;
        for (int k = 0; k < BATCH; ++k) v += darow[k] * t[k * EMB + j];
    }
    float sq = (j < EMB) ? v * v : 0.0f;
#pragma unroll
    for (int off = 32; off > 0; off >>= 1) sq += __shfl_down(sq, off, 64);
    __shared__ float partial[2];
    if ((j & 63) == 0) partial[j >> 6] = sq;
    __syncthreads();
    float norm = sqrtf(partial[0] + partial[1]);
    float inv = 1.0f / fmaxf(norm, 1e-12f);
    if (j < EMB) {
        float s = v * inv;
        sess[b * EMB + j] = s;
        float a = acc[b * EMB + j] + s;
        acc[b * EMB + j] = a;
        if (final_layer) out[b * EMB + j] = a * (1.0f / 3.0f);
    }
}

extern "C" void kernel_launch(void* const* d_in, const int* in_sizes, int n_in,
                              void* d_out, int out_size, void* d_ws, size_t ws_size,
                              hipStream_t stream) {
    const float* embedding = (const float*)d_in[0];   // [100000,112]
    const float* adj_vals  = (const float*)d_in[1];   // [1e6]
    const int*   adj_rows  = (const int*)d_in[2];     // [1e6]
    const int*   adj_cols  = (const int*)d_in[3];     // [1e6]
    const float* D         = (const float*)d_in[4];   // [512,512]
    const float* A         = (const float*)d_in[5];   // [512,512]
    const int*   sess_item = (const int*)d_in[6];     // [512,50]
    const float* sess_len  = (const float*)d_in[7];   // [512,1]
    const float* w_sess    = (const float*)d_in[8];   // [2,112,112]
    float* out = (float*)d_out;                       // [512,112]

    const size_t NODE_BYTES = (size_t)N_NODE * EMB * sizeof(float);  // 44,800,000
    char* ws = (char*)d_ws;
    float* next1 = (float*)(ws);                          // 44.8 MB: S(emb)
    float* item  = (float*)(ws + NODE_BYTES);             // 44.8 MB: item_emb
    int*   off   = (int*)(ws + 2 * NODE_BYTES);           // 400,000 B
    int*   bsum  = (int*)(ws + 2 * NODE_BYTES + 400128);  // 512 B
    char*  perm_region = ws + 2 * NODE_BYTES + 400640;    // 4,000,000 B
    int*   perm  = (int*)perm_region;
    // perm region is dead after spmm layer 2 -> reuse for sessconv scratch
    float* DA    = (float*)perm_region;                   // 1,048,576 B
    float* sess  = (float*)(perm_region + 1048576);       // 229,376 B
    float* tbuf  = (float*)(perm_region + 1048576 + 229376);
    float* accb  = (float*)(perm_region + 1048576 + 2 * 229376);

    // --- build CSR permutation (counting sort by adj_rows) ---
    hipMemsetAsync(off, 0, N_NODE * sizeof(int), stream);
    {
        int blocks = (NNZ + 255) / 256;
        hist_kernel<<<blocks, 256, 0, stream>>>(adj_rows, off, NNZ);
        int nb = (N_NODE + SCAN_B - 1) / SCAN_B;  // 98
        scan_block_kernel<<<nb, 256, 0, stream>>>(off, bsum, N_NODE);
        scan_sums_kernel<<<1, 128, 0, stream>>>(bsum, nb);
        scan_add_kernel<<<(N_NODE + 255) / 256, 256, 0, stream>>>(off, bsum, N_NODE);
        scatter_kernel<<<blocks, 256, 0, stream>>>(adj_rows, off, perm, NNZ);
        // off[r] is now the END pointer of row r's segment in perm
    }

    // --- hyperconv: next1 = S(emb); item = (S(next1) + next1 + emb)/3 ---
    {
        int grid = (N_NODE + 1) / 2;  // 2 rows per 256-thread block
        spmm_csr_kernel<<<grid, 256, 0, stream>>>(embedding, nullptr, off, perm,
                                                  adj_cols, adj_vals, next1, 0);
        spmm_csr_kernel<<<grid, 256, 0, stream>>>(next1, embedding, off, perm,
                                                  adj_cols, adj_vals, item, 1);
    }

    // --- sessconv (perm region now reused: DA/sess/tbuf/accb) ---
    {
        dim3 grid(BATCH / TS, BATCH / TS);
        dim3 block(TS, TS);
        gemm_da_kernel<<<grid, block, 0, stream>>>(D, A, DA);
    }
    pool_kernel<<<BATCH, 128, 0, stream>>>(item, sess_item, sess_len, sess, accb);
    for (int i = 0; i < LAYERS; ++i) {
        lin_kernel<<<BATCH, 128, 0, stream>>>(sess, w_sess + (size_t)i * EMB * EMB, tbuf);
        damul_norm_kernel<<<BATCH, 128, 0, stream>>>(DA, tbuf, sess, accb, out,
                                                     i == LAYERS - 1);
    }
}

// Round 3
// 422.882 us; speedup vs baseline: 7.3157x; 2.0310x over previous
//
#include <hip/hip_runtime.h>
#include <hip/hip_bf16.h>

#define N_NODE 100000
#define EMB 112
#define EMB2 56   // float2 per row
#define NNZ 1000000
#define BATCH 512
#define SEQL 50
#define LAYERS 2

// ---------------------------------------------------------------------------
// Counting sort of edges by destination row -> sorted (col, val) pairs.
// ---------------------------------------------------------------------------
__global__ void hist_kernel(const int* __restrict__ rows, int* __restrict__ cnt,
                            int nnz) {
    int i = blockIdx.x * blockDim.x + threadIdx.x;
    if (i < nnz) atomicAdd(&cnt[rows[i]], 1);
}

// In-place exclusive scan, 1024 elements per block (256 thr x 4), block sums out.
#define SCAN_B 1024
__global__ void scan_block_kernel(int* __restrict__ a, int* __restrict__ bsum,
                                  int n) {
    __shared__ int s[256];
    int t = threadIdx.x;
    int base = blockIdx.x * SCAN_B + t * 4;
    int v0 = (base + 0 < n) ? a[base + 0] : 0;
    int v1 = (base + 1 < n) ? a[base + 1] : 0;
    int v2 = (base + 2 < n) ? a[base + 2] : 0;
    int v3 = (base + 3 < n) ? a[base + 3] : 0;
    int tsum = v0 + v1 + v2 + v3;
    s[t] = tsum;
    __syncthreads();
#pragma unroll
    for (int d = 1; d < 256; d <<= 1) {
        int x = (t >= d) ? s[t - d] : 0;
        __syncthreads();
        s[t] += x;
        __syncthreads();
    }
    int excl = s[t] - tsum;
    if (t == 255) bsum[blockIdx.x] = s[255];
    if (base + 0 < n) a[base + 0] = excl;
    if (base + 1 < n) a[base + 1] = excl + v0;
    if (base + 2 < n) a[base + 2] = excl + v0 + v1;
    if (base + 3 < n) a[base + 3] = excl + v0 + v1 + v2;
}

__global__ void scan_sums_kernel(int* __restrict__ bsum, int nb) {
    __shared__ int s[128];
    int t = threadIdx.x;
    int v = (t < nb) ? bsum[t] : 0;
    s[t] = v;
    __syncthreads();
#pragma unroll
    for (int d = 1; d < 128; d <<= 1) {
        int x = (t >= d) ? s[t - d] : 0;
        __syncthreads();
        s[t] += x;
        __syncthreads();
    }
    if (t < nb) bsum[t] = s[t] - v;  // exclusive
}

__global__ void scan_add_kernel(int* __restrict__ a, const int* __restrict__ bsum,
                                int n) {
    int i = blockIdx.x * blockDim.x + threadIdx.x;
    if (i < n) a[i] += bsum[i >> 10];
}

// p = atomicAdd(&off[r],1): writes sorted (col,val); off[r] becomes row-end ptr.
__global__ void scatter_kernel(const int* __restrict__ rows,
                               const int* __restrict__ cols,
                               const float* __restrict__ vals,
                               int* __restrict__ off, int2* __restrict__ edges,
                               int nnz) {
    int i = blockIdx.x * blockDim.x + threadIdx.x;
    if (i >= nnz) return;
    int r = rows[i];
    int p = atomicAdd(&off[r], 1);
    edges[p] = make_int2(cols[i], __float_as_int(vals[i]));
}

// flags[it-1] = 1 for every item appearing in any session (benign races).
__global__ void flag_kernel(const int* __restrict__ items,
                            int* __restrict__ flags) {
    int i = blockIdx.x * blockDim.x + threadIdx.x;
    if (i < BATCH * SEQL) {
        int it = items[i];
        if (it > 0) flags[it - 1] = 1;
    }
}

// ---------------------------------------------------------------------------
// CSR gather SpMM, row per 64-lane wave, float2 per lane (56 active lanes).
// Unroll-4 software pipeline: 4 independent 448B row gathers in flight.
// flags/map non-null => compute only flagged rows, write compacted at map[r].
// fuse_final: out = (spmm + cur[r] + emb[r]) / 3.
// ---------------------------------------------------------------------------
__global__ void spmm_csr_kernel(const float* __restrict__ cur,
                                const float* __restrict__ emb,
                                const int* __restrict__ rend,
                                const int2* __restrict__ edges,
                                const int* __restrict__ flags,
                                const int* __restrict__ map,
                                float* __restrict__ outm, int fuse_final) {
    int wid = threadIdx.x >> 6;
    int lane = threadIdx.x & 63;
    int r = (blockIdx.x << 2) + wid;
    if (r >= N_NODE) return;
    if (flags && !flags[r]) return;
    int beg = (r == 0) ? 0 : rend[r - 1];
    int end = rend[r];
    int lf = (lane < EMB2) ? lane : (EMB2 - 1);  // clamp keeps lanes 56-63 in-bounds
    const float2* base = (const float2*)cur;
    float2 acc = make_float2(0.0f, 0.0f);
    int k = beg;
    for (; k + 4 <= end; k += 4) {
        int2 e0 = edges[k + 0];
        int2 e1 = edges[k + 1];
        int2 e2 = edges[k + 2];
        int2 e3 = edges[k + 3];
        float2 x0 = base[e0.x * EMB2 + lf];
        float2 x1 = base[e1.x * EMB2 + lf];
        float2 x2 = base[e2.x * EMB2 + lf];
        float2 x3 = base[e3.x * EMB2 + lf];
        float v0 = __int_as_float(e0.y), v1 = __int_as_float(e1.y);
        float v2 = __int_as_float(e2.y), v3 = __int_as_float(e3.y);
        acc.x += v0 * x0.x; acc.y += v0 * x0.y;
        acc.x += v1 * x1.x; acc.y += v1 * x1.y;
        acc.x += v2 * x2.x; acc.y += v2 * x2.y;
        acc.x += v3 * x3.x; acc.y += v3 * x3.y;
    }
    for (; k < end; ++k) {
        int2 e = edges[k];
        float2 x = base[e.x * EMB2 + lf];
        float v = __int_as_float(e.y);
        acc.x += v * x.x; acc.y += v * x.y;
    }
    if (lane < EMB2) {
        int orow = map ? map[r] : r;
        size_t o = (size_t)r * EMB2 + lane;
        if (fuse_final) {
            float2 c = ((const float2*)cur)[o];
            float2 eb = ((const float2*)emb)[o];
            acc.x = (acc.x + c.x + eb.x) * (1.0f / 3.0f);
            acc.y = (acc.y + c.y + eb.y) * (1.0f / 3.0f);
        }
        ((float2*)outm)[(size_t)orow * EMB2 + lane] = acc;
    }
}

// ---------------------------------------------------------------------------
// Pool over compacted item_emb: sess[b] = sum_l item_c[map[it-1]] / len[b].
// ---------------------------------------------------------------------------
__global__ void pool_kernel(const float* __restrict__ item_c,
                            const int* __restrict__ map,
                            const int* __restrict__ items,
                            const float* __restrict__ slen,
                            float* __restrict__ sess, float* __restrict__ acc) {
    int b = blockIdx.x;
    int f = threadIdx.x;
    if (f >= EMB) return;
    float s = 0.0f;
    for (int l = 0; l < SEQL; ++l) {
        int it = items[b * SEQL + l];
        if (it > 0) s += item_c[(size_t)map[it - 1] * EMB + f];
    }
    s /= slen[b];
    sess[b * EMB + f] = s;
    acc[b * EMB + f] = s;
}

// ---------------------------------------------------------------------------
// DA = D @ A, 512x512x512 fp32, 16x16 LDS-tiled (no fp32 MFMA on CDNA4).
// ---------------------------------------------------------------------------
#define TS 16
__global__ void gemm_da_kernel(const float* __restrict__ D,
                               const float* __restrict__ A,
                               float* __restrict__ DA) {
    __shared__ float sD[TS][TS];
    __shared__ float sA[TS][TS + 1];
    int row = blockIdx.y * TS + threadIdx.y;
    int col = blockIdx.x * TS + threadIdx.x;
    float acc = 0.0f;
    for (int k0 = 0; k0 < BATCH; k0 += TS) {
        sD[threadIdx.y][threadIdx.x] = D[row * BATCH + k0 + threadIdx.x];
        sA[threadIdx.y][threadIdx.x] = A[(k0 + threadIdx.y) * BATCH + col];
        __syncthreads();
#pragma unroll
        for (int k = 0; k < TS; ++k)
            acc += sD[threadIdx.y][k] * sA[k][threadIdx.x];
        __syncthreads();
    }
    DA[row * BATCH + col] = acc;
}

// ---------------------------------------------------------------------------
// t = sess @ W^T
// ---------------------------------------------------------------------------
__global__ void lin_kernel(const float* __restrict__ sess,
                           const float* __restrict__ W,
                           float* __restrict__ t) {
    __shared__ float srow[EMB];
    int b = blockIdx.x;
    int j = threadIdx.x;
    if (j < EMB) srow[j] = sess[b * EMB + j];
    __syncthreads();
    if (j >= EMB) return;
    float a = 0.0f;
    for (int k = 0; k < EMB; ++k) a += srow[k] * W[j * EMB + k];
    t[b * EMB + j] = a;
}

// ---------------------------------------------------------------------------
// s2 = l2norm_row(DA @ t); sess = s2; acc += s2; if final: out = acc / 3.
// ---------------------------------------------------------------------------
__global__ void damul_norm_kernel(const float* __restrict__ DA,
                                  const float* __restrict__ t,
                                  float* __restrict__ sess,
                                  float* __restrict__ acc,
                                  float* __restrict__ out, int final_layer) {
    int b = blockIdx.x;
    int j = threadIdx.x;  // 0..127
    float v = 0.0f;
    if (j < EMB) {
        const float* darow = DA + (size_t)b * BATCH;
        for (int k = 0; k < BATCH; ++k) v += darow[k] * t[k * EMB + j];
    }
    float sq = (j < EMB) ? v * v : 0.0f;
#pragma unroll
    for (int off = 32; off > 0; off >>= 1) sq += __shfl_down(sq, off, 64);
    __shared__ float partial[2];
    if ((j & 63) == 0) partial[j >> 6] = sq;
    __syncthreads();
    float norm = sqrtf(partial[0] + partial[1]);
    float inv = 1.0f / fmaxf(norm, 1e-12f);
    if (j < EMB) {
        float s = v * inv;
        sess[b * EMB + j] = s;
        float a = acc[b * EMB + j] + s;
        acc[b * EMB + j] = a;
        if (final_layer) out[b * EMB + j] = a * (1.0f / 3.0f);
    }
}

extern "C" void kernel_launch(void* const* d_in, const int* in_sizes, int n_in,
                              void* d_out, int out_size, void* d_ws, size_t ws_size,
                              hipStream_t stream) {
    const float* embedding = (const float*)d_in[0];
    const float* adj_vals  = (const float*)d_in[1];
    const int*   adj_rows  = (const int*)d_in[2];
    const int*   adj_cols  = (const int*)d_in[3];
    const float* D         = (const float*)d_in[4];
    const float* A         = (const float*)d_in[5];
    const int*   sess_item = (const int*)d_in[6];
    const float* sess_len  = (const float*)d_in[7];
    const float* w_sess    = (const float*)d_in[8];
    float* out = (float*)d_out;

    // Workspace layout (all offsets 128B-aligned); total ~67.2 MB
    char* ws = (char*)d_ws;
    float* next1  = (float*)(ws);                  // 44,800,000
    int2*  edges  = (int2*)(ws + 44800000);        //  8,000,000
    int*   off    = (int*)(ws + 52800000);         //    400,128
    int*   bsum   = (int*)(ws + 53200128);         //        512
    int*   flags  = (int*)(ws + 53200640);         //    400,128
    int*   map    = (int*)(ws + 53600768);         //    400,128
    float* item_c = (float*)(ws + 54000896);       // 11,468,800 (25600 rows max)
    float* DA     = (float*)(ws + 65469696);       //  1,048,576
    float* sess   = (float*)(ws + 66518272);       //    229,376
    float* tbuf   = (float*)(ws + 66747648);       //    229,376
    float* accb   = (float*)(ws + 66977024);       //    229,376

    int nb = (N_NODE + SCAN_B - 1) / SCAN_B;  // 98

    hipMemsetAsync(off, 0, N_NODE * sizeof(int), stream);
    hipMemsetAsync(flags, 0, N_NODE * sizeof(int), stream);

    // CSR build: histogram -> scan -> rank-scatter of sorted (col,val)
    {
        int blocks = (NNZ + 255) / 256;
        hist_kernel<<<blocks, 256, 0, stream>>>(adj_rows, off, NNZ);
        scan_block_kernel<<<nb, 256, 0, stream>>>(off, bsum, N_NODE);
        scan_sums_kernel<<<1, 128, 0, stream>>>(bsum, nb);
        scan_add_kernel<<<(N_NODE + 255) / 256, 256, 0, stream>>>(off, bsum, N_NODE);
        scatter_kernel<<<blocks, 256, 0, stream>>>(adj_rows, adj_cols, adj_vals,
                                                   off, edges, NNZ);
        // off[r] is now END of row r's segment
    }

    // Needed-row flags from sessions; map = exclusive scan of flags (compaction)
    flag_kernel<<<(BATCH * SEQL + 255) / 256, 256, 0, stream>>>(sess_item, flags);
    hipMemcpyAsync(map, flags, N_NODE * sizeof(int), hipMemcpyDeviceToDevice, stream);
    scan_block_kernel<<<nb, 256, 0, stream>>>(map, bsum, N_NODE);
    scan_sums_kernel<<<1, 128, 0, stream>>>(bsum, nb);
    scan_add_kernel<<<(N_NODE + 255) / 256, 256, 0, stream>>>(map, bsum, N_NODE);

    // hyperconv
    {
        int grid = (N_NODE + 3) / 4;  // row per wave, 4 waves per block
        spmm_csr_kernel<<<grid, 256, 0, stream>>>(embedding, nullptr, off, edges,
                                                  nullptr, nullptr, next1, 0);
        spmm_csr_kernel<<<grid, 256, 0, stream>>>(next1, embedding, off, edges,
                                                  flags, map, item_c, 1);
    }

    // sessconv
    {
        dim3 grid(BATCH / TS, BATCH / TS);
        dim3 block(TS, TS);
        gemm_da_kernel<<<grid, block, 0, stream>>>(D, A, DA);
    }
    pool_kernel<<<BATCH, 128, 0, stream>>>(item_c, map, sess_item, sess_len,
                                           sess, accb);
    for (int i = 0; i < LAYERS; ++i) {
        lin_kernel<<<BATCH, 128, 0, stream>>>(sess, w_sess + (size_t)i * EMB * EMB, tbuf);
        damul_norm_kernel<<<BATCH, 128, 0, stream>>>(DA, tbuf, sess, accb, out,
                                                     i == LAYERS - 1);
    }
}

// Round 4
// 379.950 us; speedup vs baseline: 8.1423x; 1.1130x over previous
//
#include <hip/hip_runtime.h>
#include <hip/hip_bf16.h>

#define N_NODE 100000
#define EMB 112
#define EMB2 56   // packed bf16x2 (uint) or float2 per row
#define NNZ 1000000
#define BATCH 512
#define SEQL 50
#define LAYERS 2

typedef unsigned int uint32;

// fp32 -> bf16 with round-to-nearest-even (no NaN in this data)
__device__ __forceinline__ unsigned short f2bf(float f) {
    uint32 u = __float_as_uint(f);
    u = (u + 0x7fffu + ((u >> 16) & 1u)) >> 16;
    return (unsigned short)u;
}
__device__ __forceinline__ uint32 pack_bf2(float x, float y) {
    return (uint32)f2bf(x) | ((uint32)f2bf(y) << 16);
}
__device__ __forceinline__ float2 unpack_bf2(uint32 p) {
    float2 r;
    r.x = __uint_as_float(p << 16);
    r.y = __uint_as_float(p & 0xffff0000u);
    return r;
}

#define NPAD 100352  // N_NODE rounded up to 1024 multiple (98 scan blocks)

// ---------------------------------------------------------------------------
// prep: (a) convert embedding fp32 -> packed bf16; (b) histogram of adj_rows
// into off; (c) session flags into flags and map.
// ---------------------------------------------------------------------------
__global__ void prep_kernel(const float2* __restrict__ embf2,
                            uint32* __restrict__ embb,
                            const int* __restrict__ rows, int* __restrict__ off,
                            const int* __restrict__ items,
                            int* __restrict__ flags, int* __restrict__ map) {
    int i = blockIdx.x * blockDim.x + threadIdx.x;
    if (i < N_NODE * EMB2) {
        float2 v = embf2[i];
        embb[i] = pack_bf2(v.x, v.y);
    }
    if (i < NNZ) atomicAdd(&off[rows[i]], 1);
    if (i < BATCH * SEQL) {
        int it = items[i];
        if (it > 0) { flags[it - 1] = 1; map[it - 1] = 1; }
    }
}

// ---------------------------------------------------------------------------
// Scan: in-place exclusive scan of [off | map] (2*NPAD elements), 1024/block.
// ---------------------------------------------------------------------------
#define SCAN_B 1024
__global__ void scan_block_kernel(int* __restrict__ a, int* __restrict__ bsum,
                                  int n) {
    __shared__ int s[256];
    int t = threadIdx.x;
    int base = blockIdx.x * SCAN_B + t * 4;
    int v0 = (base + 0 < n) ? a[base + 0] : 0;
    int v1 = (base + 1 < n) ? a[base + 1] : 0;
    int v2 = (base + 2 < n) ? a[base + 2] : 0;
    int v3 = (base + 3 < n) ? a[base + 3] : 0;
    int tsum = v0 + v1 + v2 + v3;
    s[t] = tsum;
    __syncthreads();
#pragma unroll
    for (int d = 1; d < 256; d <<= 1) {
        int x = (t >= d) ? s[t - d] : 0;
        __syncthreads();
        s[t] += x;
        __syncthreads();
    }
    int excl = s[t] - tsum;
    if (t == 255) bsum[blockIdx.x] = s[255];
    if (base + 0 < n) a[base + 0] = excl;
    if (base + 1 < n) a[base + 1] = excl + v0;
    if (base + 2 < n) a[base + 2] = excl + v0 + v1;
    if (base + 3 < n) a[base + 3] = excl + v0 + v1 + v2;
}

// Segmented exclusive scan of block sums: blocks [0,seg) and [seg,nb) restart.
__global__ void scan_sums_kernel(int* __restrict__ bsum, int nb, int seg) {
    __shared__ int s[256];
    int t = threadIdx.x;
    int v = (t < nb) ? bsum[t] : 0;
    s[t] = v;
    __syncthreads();
#pragma unroll
    for (int d = 1; d < 256; d <<= 1) {
        int x = (t >= d) ? s[t - d] : 0;
        __syncthreads();
        s[t] += x;
        __syncthreads();
    }
    int base = s[seg - 1];  // inclusive total of first segment
    if (t < nb) bsum[t] = (s[t] - v) - (t >= seg ? base : 0);
}

__global__ void scan_add_kernel(int* __restrict__ a, const int* __restrict__ bsum,
                                int n) {
    int i = blockIdx.x * blockDim.x + threadIdx.x;
    if (i < n) a[i] += bsum[i >> 10];
}

// rank-scatter sorted (col, val); off[r] becomes row-end pointer.
__global__ void scatter_kernel(const int* __restrict__ rows,
                               const int* __restrict__ cols,
                               const float* __restrict__ vals,
                               int* __restrict__ off, int2* __restrict__ edges,
                               int nnz) {
    int i = blockIdx.x * blockDim.x + threadIdx.x;
    if (i >= nnz) return;
    int r = rows[i];
    int p = atomicAdd(&off[r], 1);
    edges[p] = make_int2(cols[i], __float_as_int(vals[i]));
}

// ---------------------------------------------------------------------------
// CSR gather SpMM over packed-bf16 rows; row per 64-lane wave.
// Lanes cooperatively prefetch up to 64 edge descriptors, then __shfl
// broadcast; k-loop's only memory ops are the (independent) row gathers.
// fuse_final: out_f32[map[r]] = (spmm + cur_bf16[r] + emb_f32[r]) / 3.
// else:       out_bf16[r] = spmm.
// ---------------------------------------------------------------------------
__global__ __launch_bounds__(256, 8)
void spmm_csr_kernel(const uint32* __restrict__ curb,
                     const float2* __restrict__ embf,
                     const int* __restrict__ rend,
                     const int2* __restrict__ edges,
                     const int* __restrict__ flags,
                     const int* __restrict__ map,
                     void* __restrict__ outm, int fuse_final) {
    int wid = threadIdx.x >> 6;
    int lane = threadIdx.x & 63;
    int r = (blockIdx.x << 2) + wid;
    if (r >= N_NODE) return;
    if (flags && !flags[r]) return;
    int beg = (r == 0) ? 0 : rend[r - 1];
    int end = rend[r];
    int len = end - beg;
    int lf = (lane < EMB2) ? lane : (EMB2 - 1);
    float2 acc = make_float2(0.0f, 0.0f);
    for (int base = 0; base < len; base += 64) {
        int m = len - base; if (m > 64) m = 64;
        int2 e = (lane < m) ? edges[beg + base + lane] : make_int2(0, 0);
        int k = 0;
        for (; k + 4 <= m; k += 4) {
            int c0 = __shfl(e.x, k + 0); float v0 = __int_as_float(__shfl(e.y, k + 0));
            int c1 = __shfl(e.x, k + 1); float v1 = __int_as_float(__shfl(e.y, k + 1));
            int c2 = __shfl(e.x, k + 2); float v2 = __int_as_float(__shfl(e.y, k + 2));
            int c3 = __shfl(e.x, k + 3); float v3 = __int_as_float(__shfl(e.y, k + 3));
            uint32 p0 = curb[c0 * EMB2 + lf];
            uint32 p1 = curb[c1 * EMB2 + lf];
            uint32 p2 = curb[c2 * EMB2 + lf];
            uint32 p3 = curb[c3 * EMB2 + lf];
            float2 x0 = unpack_bf2(p0), x1 = unpack_bf2(p1);
            float2 x2 = unpack_bf2(p2), x3 = unpack_bf2(p3);
            acc.x += v0 * x0.x; acc.y += v0 * x0.y;
            acc.x += v1 * x1.x; acc.y += v1 * x1.y;
            acc.x += v2 * x2.x; acc.y += v2 * x2.y;
            acc.x += v3 * x3.x; acc.y += v3 * x3.y;
        }
        for (; k < m; ++k) {
            int c = __shfl(e.x, k); float v = __int_as_float(__shfl(e.y, k));
            float2 x = unpack_bf2(curb[c * EMB2 + lf]);
            acc.x += v * x.x; acc.y += v * x.y;
        }
    }
    if (lane < EMB2) {
        if (fuse_final) {
            size_t o = (size_t)r * EMB2 + lane;
            float2 c = unpack_bf2(curb[o]);
            float2 eb = embf[o];
            acc.x = (acc.x + c.x + eb.x) * (1.0f / 3.0f);
            acc.y = (acc.y + c.y + eb.y) * (1.0f / 3.0f);
            ((float2*)outm)[(size_t)map[r] * EMB2 + lane] = acc;
        } else {
            ((uint32*)outm)[(size_t)r * EMB2 + lane] = pack_bf2(acc.x, acc.y);
        }
    }
}

// ---------------------------------------------------------------------------
// Pool over compacted fp32 item_emb.
// ---------------------------------------------------------------------------
__global__ void pool_kernel(const float* __restrict__ item_c,
                            const int* __restrict__ map,
                            const int* __restrict__ items,
                            const float* __restrict__ slen,
                            float* __restrict__ sess, float* __restrict__ acc) {
    int b = blockIdx.x;
    int f = threadIdx.x;
    if (f >= EMB) return;
    float s = 0.0f;
    for (int l = 0; l < SEQL; ++l) {
        int it = items[b * SEQL + l];
        if (it > 0) s += item_c[(size_t)map[it - 1] * EMB + f];
    }
    s /= slen[b];
    sess[b * EMB + f] = s;
    acc[b * EMB + f] = s;
}

// ---------------------------------------------------------------------------
// DA = D @ A, 512^3 fp32. 64x64 tile, 16x16 threads, 4x4 per thread, BK=16.
// ---------------------------------------------------------------------------
__global__ __launch_bounds__(256)
void gemm_da_kernel(const float* __restrict__ D, const float* __restrict__ A,
                    float* __restrict__ DA) {
    __shared__ float sDt[16][68];  // sDt[k][m]: D transposed; 272B rows keep 16B align
    __shared__ float sA[16][68];   // sA[k][n]
    int t = threadIdx.x;
    int tx = t & 15, ty = t >> 4;
    int m0 = blockIdx.y * 64, n0 = blockIdx.x * 64;
    float acc[4][4];
#pragma unroll
    for (int i = 0; i < 4; ++i)
#pragma unroll
        for (int j = 0; j < 4; ++j) acc[i][j] = 0.0f;

    int dm = t >> 2, dk = (t & 3) * 4;       // D: row m0+dm, cols k0+dk..+3
    int ak = t >> 4, an = (t & 15) * 4;      // A: row k0+ak, cols n0+an..+3
    for (int k0 = 0; k0 < BATCH; k0 += 16) {
        float4 dv = *(const float4*)(D + (size_t)(m0 + dm) * BATCH + k0 + dk);
        float4 av = *(const float4*)(A + (size_t)(k0 + ak) * BATCH + n0 + an);
        __syncthreads();
        sDt[dk + 0][dm] = dv.x;
        sDt[dk + 1][dm] = dv.y;
        sDt[dk + 2][dm] = dv.z;
        sDt[dk + 3][dm] = dv.w;
        *(float4*)&sA[ak][an] = av;
        __syncthreads();
#pragma unroll
        for (int k = 0; k < 16; ++k) {
            float4 a = *(const float4*)&sDt[k][ty * 4];
            float4 b = *(const float4*)&sA[k][tx * 4];
            float ar[4] = {a.x, a.y, a.z, a.w};
            float br[4] = {b.x, b.y, b.z, b.w};
#pragma unroll
            for (int i = 0; i < 4; ++i)
#pragma unroll
                for (int j = 0; j < 4; ++j) acc[i][j] += ar[i] * br[j];
        }
    }
#pragma unroll
    for (int i = 0; i < 4; ++i) {
        float4 o = make_float4(acc[i][0], acc[i][1], acc[i][2], acc[i][3]);
        *(float4*)(DA + (size_t)(m0 + ty * 4 + i) * BATCH + n0 + tx * 4) = o;
    }
}

// ---------------------------------------------------------------------------
// t = sess @ W^T
// ---------------------------------------------------------------------------
__global__ void lin_kernel(const float* __restrict__ sess,
                           const float* __restrict__ W,
                           float* __restrict__ t) {
    __shared__ float srow[EMB];
    int b = blockIdx.x;
    int j = threadIdx.x;
    if (j < EMB) srow[j] = sess[b * EMB + j];
    __syncthreads();
    if (j >= EMB) return;
    float a = 0.0f;
#pragma unroll 4
    for (int k = 0; k < EMB; ++k) a += srow[k] * W[j * EMB + k];
    t[b * EMB + j] = a;
}

// ---------------------------------------------------------------------------
// s2 = l2norm_row(DA @ t); sess = s2; acc += s2; if final: out = acc / 3.
// ---------------------------------------------------------------------------
__global__ void damul_norm_kernel(const float* __restrict__ DA,
                                  const float* __restrict__ t,
                                  float* __restrict__ sess,
                                  float* __restrict__ acc,
                                  float* __restrict__ out, int final_layer) {
    int b = blockIdx.x;
    int j = threadIdx.x;  // 0..127
    float v = 0.0f;
    if (j < EMB) {
        const float* darow = DA + (size_t)b * BATCH;
        for (int k0 = 0; k0 < BATCH; k0 += 4) {
            float4 d4 = *(const float4*)(darow + k0);
            float t0 = t[(k0 + 0) * EMB + j];
            float t1 = t[(k0 + 1) * EMB + j];
            float t2 = t[(k0 + 2) * EMB + j];
            float t3 = t[(k0 + 3) * EMB + j];
            v += d4.x * t0 + d4.y * t1 + d4.z * t2 + d4.w * t3;
        }
    }
    float sq = (j < EMB) ? v * v : 0.0f;
#pragma unroll
    for (int off = 32; off > 0; off >>= 1) sq += __shfl_down(sq, off, 64);
    __shared__ float partial[2];
    if ((j & 63) == 0) partial[j >> 6] = sq;
    __syncthreads();
    float norm = sqrtf(partial[0] + partial[1]);
    float inv = 1.0f / fmaxf(norm, 1e-12f);
    if (j < EMB) {
        float s = v * inv;
        sess[b * EMB + j] = s;
        float a = acc[b * EMB + j] + s;
        acc[b * EMB + j] = a;
        if (final_layer) out[b * EMB + j] = a * (1.0f / 3.0f);
    }
}

extern "C" void kernel_launch(void* const* d_in, const int* in_sizes, int n_in,
                              void* d_out, int out_size, void* d_ws, size_t ws_size,
                              hipStream_t stream) {
    const float* embedding = (const float*)d_in[0];
    const float* adj_vals  = (const float*)d_in[1];
    const int*   adj_rows  = (const int*)d_in[2];
    const int*   adj_cols  = (const int*)d_in[3];
    const float* D         = (const float*)d_in[4];
    const float* A         = (const float*)d_in[5];
    const int*   sess_item = (const int*)d_in[6];
    const float* sess_len  = (const float*)d_in[7];
    const float* w_sess    = (const float*)d_in[8];
    float* out = (float*)d_out;

    // Workspace layout (128B-aligned offsets); total ~67.3 MB
    char* ws = (char*)d_ws;
    uint32* embb   = (uint32*)(ws);                 // 22,400,000 bf16 embedding
    uint32* next1b = (uint32*)(ws + 22400000);      // 22,400,000 bf16 S(emb)
    int2*   edges  = (int2*)(ws + 44800000);        //  8,000,000
    int*    off    = (int*)(ws + 52800000);         //    401,408 (NPAD ints)
    int*    mapv   = (int*)(ws + 53201408);         //    401,408
    int*    flags  = (int*)(ws + 53602816);         //    401,408
    int*    bsum   = (int*)(ws + 54004224);         //      1,024
    float*  item_c = (float*)(ws + 54005248);       // 11,468,800 (25600 rows)
    float*  DA     = (float*)(ws + 65474048);       //  1,048,576
    float*  sess   = (float*)(ws + 66522624);       //    229,376
    float*  tbuf   = (float*)(ws + 66752000);       //    229,376
    float*  accb   = (float*)(ws + 66981376);       //    229,376

    // zero off|map|flags in one shot (contiguous)
    hipMemsetAsync(off, 0, 3 * NPAD * sizeof(int), stream);

    // prep: bf16 convert + histogram + flags
    prep_kernel<<<(N_NODE * EMB2 + 255) / 256, 256, 0, stream>>>(
        (const float2*)embedding, embb, adj_rows, off, sess_item, flags, mapv);

    // fused exclusive scans of off (rows CSR) and map (compaction), segmented
    {
        int n2 = 2 * NPAD;                     // 200704
        int nb2 = n2 / SCAN_B;                 // 196
        scan_block_kernel<<<nb2, 256, 0, stream>>>(off, bsum, n2);
        scan_sums_kernel<<<1, 256, 0, stream>>>(bsum, nb2, NPAD / SCAN_B);
        scan_add_kernel<<<(n2 + 255) / 256, 256, 0, stream>>>(off, bsum, n2);
    }
    scatter_kernel<<<(NNZ + 255) / 256, 256, 0, stream>>>(adj_rows, adj_cols,
                                                          adj_vals, off, edges, NNZ);

    // hyperconv (bf16 gathers, fp32 accumulate)
    {
        int grid = (N_NODE + 3) / 4;
        spmm_csr_kernel<<<grid, 256, 0, stream>>>(embb, nullptr, off, edges,
                                                  nullptr, nullptr, next1b, 0);
        spmm_csr_kernel<<<grid, 256, 0, stream>>>(next1b, (const float2*)embedding,
                                                  off, edges, flags, mapv, item_c, 1);
    }

    // sessconv
    {
        dim3 grid(BATCH / 64, BATCH / 64);
        gemm_da_kernel<<<grid, 256, 0, stream>>>(D, A, DA);
    }
    pool_kernel<<<BATCH, 128, 0, stream>>>(item_c, mapv, sess_item, sess_len,
                                           sess, accb);
    for (int i = 0; i < LAYERS; ++i) {
        lin_kernel<<<BATCH, 128, 0, stream>>>(sess, w_sess + (size_t)i * EMB * EMB, tbuf);
        damul_norm_kernel<<<BATCH, 128, 0, stream>>>(DA, tbuf, sess, accb, out,
                                                     i == LAYERS - 1);
    }
}